// Round 1
// baseline (728.919 us; speedup 1.0000x reference)
//
#include <hip/hip_runtime.h>
#include <stdint.h>

// SparseLinear: out[m][n] = sum_k x[m][k] * W[n][k] * mask[n][k]
// M = B*S = 8192, N = 4096, K = 4096, fp32 in/out, bf16-tolerance check.
// Strategy: fold mask into W, convert x/W to bf16 in workspace, then
// m97-structure bf16 MFMA GEMM (128x128 tile, BK=64, global_load_lds w=16).

static constexpr int Mdim = 8192;
static constexpr int Ndim = 4096;
static constexpr int Kdim = 4096;
static constexpr int BM = 128;
static constexpr int BN = 128;
static constexpr int BK = 64;

typedef __attribute__((ext_vector_type(8))) short short8;
typedef __attribute__((ext_vector_type(4))) float float4v;
typedef __attribute__((ext_vector_type(4))) int int4v;
typedef __attribute__((ext_vector_type(8))) unsigned short ushort8;
typedef __attribute__((ext_vector_type(4))) unsigned short ushort4v;

__device__ __forceinline__ unsigned short f32_to_bf16(float f) {
  union { float f; uint32_t u; } c; c.f = f;
  uint32_t u = c.u;
  u += 0x7fffu + ((u >> 16) & 1u);   // round-to-nearest-even (no NaNs in data)
  return (unsigned short)(u >> 16);
}

// ---------------------------------------------------------------------------
// Mask element-width detection. numpy bool_ = 1 byte; a harness might promote
// to int32 (or float32 0.0/1.0). Byte positions ==1 (mod 4) within the first
// 16 MiB are nonzero ONLY for the 1-byte layout (10% density -> ~419k hits).
// Both candidate layouts are >= 16 MiB, so the scan is always in-bounds.
// ---------------------------------------------------------------------------
__global__ void detect_mask_kernel(const unsigned char* __restrict__ m, int* __restrict__ flag) {
  int found = 0;
  const long total = 4194304;  // (16 MiB) / 4
  for (long p = blockIdx.x * (long)blockDim.x + threadIdx.x; p < total;
       p += (long)gridDim.x * blockDim.x)
    found |= (m[4 * p + 1] != 0);
  if (__any(found) && (threadIdx.x & 63) == 0) atomicOr(flag, 1);
}

// x fp32 -> bf16, 8 elements/thread (two 16B loads, one 16B store)
__global__ void cvt_x_kernel(const float* __restrict__ x, unsigned short* __restrict__ o) {
  long i = (blockIdx.x * (long)blockDim.x + threadIdx.x) * 8;
  float4v v0 = *(const float4v*)(x + i);
  float4v v1 = *(const float4v*)(x + i + 4);
  ushort8 r;
  r[0] = f32_to_bf16(v0[0]); r[1] = f32_to_bf16(v0[1]);
  r[2] = f32_to_bf16(v0[2]); r[3] = f32_to_bf16(v0[3]);
  r[4] = f32_to_bf16(v1[0]); r[5] = f32_to_bf16(v1[1]);
  r[6] = f32_to_bf16(v1[2]); r[7] = f32_to_bf16(v1[3]);
  *(ushort8*)(o + i) = r;
}

// W fp32 * mask -> bf16, 4 elements/thread; mask layout chosen by *flag
__global__ void cvt_w_kernel(const float* __restrict__ w, const unsigned char* __restrict__ mraw,
                             const int* __restrict__ flag, unsigned short* __restrict__ o) {
  long i = (blockIdx.x * (long)blockDim.x + threadIdx.x) * 4;
  float4v wv = *(const float4v*)(w + i);
  int m0, m1, m2, m3;
  if (*flag) {  // 1-byte elements
    uint32_t mb = *(const uint32_t*)(mraw + i);
    m0 = (mb & 0x000000ffu) != 0; m1 = (mb & 0x0000ff00u) != 0;
    m2 = (mb & 0x00ff0000u) != 0; m3 = (mb & 0xff000000u) != 0;
  } else {      // 4-byte elements (int32 0/1 or float32 0.0/1.0 — both: nonzero word)
    int4v mv = *(const int4v*)((const int*)mraw + i);
    m0 = mv[0] != 0; m1 = mv[1] != 0; m2 = mv[2] != 0; m3 = mv[3] != 0;
  }
  ushort4v r;
  r[0] = f32_to_bf16(m0 ? wv[0] : 0.0f);
  r[1] = f32_to_bf16(m1 ? wv[1] : 0.0f);
  r[2] = f32_to_bf16(m2 ? wv[2] : 0.0f);
  r[3] = f32_to_bf16(m3 ? wv[3] : 0.0f);
  *(ushort4v*)(o + i) = r;
}

// ---------------------------------------------------------------------------
// bf16 MFMA GEMM, B^T form: O[m][n] = sum_k X[m][k]*W[n][k].
// 256 threads = 4 waves; each wave computes 64x64 via 4x4 grid of 16x16x32.
// LDS tiles are row-major [row][k], BK=64 (row = 128 B = 8 chunks of 16 B),
// staged with global_load_lds width 16 (lane-contiguous LDS mandatory).
// ---------------------------------------------------------------------------
__global__ __launch_bounds__(256) void gemm_bt_kernel(const unsigned short* __restrict__ X,
                                                      const unsigned short* __restrict__ W,
                                                      float* __restrict__ O) {
  __shared__ short sA[BM * BK];  // 16 KiB
  __shared__ short sB[BN * BK];  // 16 KiB

  const int tid = threadIdx.x;
  const int lane = tid & 63;
  const int wave = tid >> 6;
  const int wr = wave >> 1;   // 0..1: which 64-row half
  const int wc = wave & 1;    // 0..1: which 64-col half

  const int tnCount = Ndim / BN;  // 32
  const int tm = blockIdx.x / tnCount;
  const int tn = blockIdx.x % tnCount;
  const int row0 = tm * BM;
  const int col0 = tn * BN;

  float4v acc[4][4];
#pragma unroll
  for (int i = 0; i < 4; ++i)
#pragma unroll
    for (int j = 0; j < 4; ++j) acc[i][j] = (float4v){0.f, 0.f, 0.f, 0.f};

  int srow[4], scol[4];
#pragma unroll
  for (int r = 0; r < 4; ++r) {
    int c = r * 256 + tid;     // 16B-chunk id within tile
    srow[r] = c >> 3;          // 8 chunks per 64-elem row
    scol[r] = (c & 7) * 8;     // element offset within row
  }

  const int rsel = lane & 15;         // fragment row (m or n) within 16
  const int kq = (lane >> 4) * 8;     // fragment k-offset

  for (int kt = 0; kt < Kdim; kt += BK) {
#pragma unroll
    for (int r = 0; r < 4; ++r) {
      const unsigned short* gA = X + (long)(row0 + srow[r]) * Kdim + kt + scol[r];
      const unsigned short* gB = W + (long)(col0 + srow[r]) * Kdim + kt + scol[r];
      const int loff = (r * 256 + tid) * 16;
      __builtin_amdgcn_global_load_lds((const __attribute__((address_space(1))) void*)gA,
                                       (__attribute__((address_space(3))) void*)((char*)sA + loff),
                                       16, 0, 0);
      __builtin_amdgcn_global_load_lds((const __attribute__((address_space(1))) void*)gB,
                                       (__attribute__((address_space(3))) void*)((char*)sB + loff),
                                       16, 0, 0);
    }
    __syncthreads();

#pragma unroll
    for (int ks = 0; ks < BK; ks += 32) {
      short8 a[4], b[4];
#pragma unroll
      for (int i = 0; i < 4; ++i)
        a[i] = *(const short8*)(sA + (wr * 64 + i * 16 + rsel) * BK + ks + kq);
#pragma unroll
      for (int j = 0; j < 4; ++j)
        b[j] = *(const short8*)(sB + (wc * 64 + j * 16 + rsel) * BK + ks + kq);
#pragma unroll
      for (int i = 0; i < 4; ++i)
#pragma unroll
        for (int j = 0; j < 4; ++j)
          acc[i][j] = __builtin_amdgcn_mfma_f32_16x16x32_bf16(a[i], b[j], acc[i][j], 0, 0, 0);
    }
    __syncthreads();
  }

  // C/D layout (verified m89/m91): col = lane&15, row = (lane>>4)*4 + reg
  const int ccol = lane & 15;
  const int crow = (lane >> 4) * 4;
#pragma unroll
  for (int i = 0; i < 4; ++i) {
#pragma unroll
    for (int j = 0; j < 4; ++j) {
      const long rbase = row0 + wr * 64 + i * 16 + crow;
      const long cg = col0 + wc * 64 + j * 16 + ccol;
#pragma unroll
      for (int r = 0; r < 4; ++r)
        O[(rbase + r) * (long)Ndim + cg] = acc[i][j][r];
    }
  }
}

// ---------------------------------------------------------------------------
// Fallback (only if ws too small for bf16 staging): fp32 LDS-tiled GEMM.
// ---------------------------------------------------------------------------
__global__ void gemm_fallback_kernel(const float* __restrict__ X, const float* __restrict__ Wt,
                                     const unsigned char* __restrict__ mraw,
                                     const int* __restrict__ flag, float* __restrict__ O) {
  __shared__ float sX[16][17];
  __shared__ float sW[16][17];
  const int tx = threadIdx.x & 15;
  const int ty = threadIdx.x >> 4;
  const long row = blockIdx.y * 16 + ty;
  const long colblock = blockIdx.x * 16;
  const int byteLayout = *flag;
  float acc = 0.f;
  for (int k0 = 0; k0 < Kdim; k0 += 16) {
    sX[ty][tx] = X[row * Kdim + k0 + tx];
    const long wi = (colblock + ty) * (long)Kdim + k0 + tx;
    const int mv = byteLayout ? (mraw[wi] != 0) : (((const int*)mraw)[wi] != 0);
    sW[ty][tx] = mv ? Wt[wi] : 0.f;
    __syncthreads();
#pragma unroll
    for (int k = 0; k < 16; ++k) acc += sX[ty][k] * sW[tx][k];
    __syncthreads();
  }
  O[row * Ndim + colblock + tx] = acc;
}

extern "C" void kernel_launch(void* const* d_in, const int* in_sizes, int n_in,
                              void* d_out, int out_size, void* d_ws, size_t ws_size,
                              hipStream_t stream) {
  const float* x = (const float*)d_in[0];               // [8192, 4096] fp32
  const float* w = (const float*)d_in[1];               // [4096, 4096] fp32
  const unsigned char* mask = (const unsigned char*)d_in[2];  // [4096,4096] bool (layout detected)
  float* out = (float*)d_out;                           // [8192, 4096] fp32

  const size_t xb_off = 0;
  const size_t wb_off = (size_t)Mdim * Kdim * 2;             // 67,108,864
  const size_t flag_off = wb_off + (size_t)Ndim * Kdim * 2;  // 100,663,296
  const size_t needed = flag_off + 16;

  if (ws_size >= needed) {
    unsigned short* xb = (unsigned short*)((char*)d_ws + xb_off);
    unsigned short* wb = (unsigned short*)((char*)d_ws + wb_off);
    int* flag = (int*)((char*)d_ws + flag_off);

    hipMemsetAsync(flag, 0, sizeof(int), stream);
    detect_mask_kernel<<<256, 256, 0, stream>>>(mask, flag);
    cvt_x_kernel<<<(int)(((long)Mdim * Kdim / 8) / 256), 256, 0, stream>>>(x, xb);
    cvt_w_kernel<<<(int)(((long)Ndim * Kdim / 4) / 256), 256, 0, stream>>>(w, mask, flag, wb);
    gemm_bt_kernel<<<(Mdim / BM) * (Ndim / BN), 256, 0, stream>>>(xb, wb, out);
  } else {
    int* flag = (int*)d_ws;
    hipMemsetAsync(flag, 0, sizeof(int), stream);
    detect_mask_kernel<<<256, 256, 0, stream>>>(mask, flag);
    dim3 grid(Ndim / 16, Mdim / 16);
    gemm_fallback_kernel<<<grid, 256, 0, stream>>>(x, w, mask, flag, out);
  }
}

// Round 2
// 706.721 us; speedup vs baseline: 1.0314x; 1.0314x over previous
//
#include <hip/hip_runtime.h>
#include <stdint.h>

// SparseLinear: out[m][n] = sum_k x[m][k] * W[n][k] * mask[n][k]
// M = B*S = 8192, N = 4096, K = 4096, fp32 in/out, bf16-tolerance check.
// R1: XOR-swizzled LDS chunk placement to kill the 1e8 bank conflicts seen in
// R0 (row stride 128 B = 32 banks exactly -> quad lanes piled on 4 banks).
// global_load_lds destination must stay lane-contiguous (m104/m108), so the
// swizzle permutes the GLOBAL source chunk per lane instead of the LDS dest.

static constexpr int Mdim = 8192;
static constexpr int Ndim = 4096;
static constexpr int Kdim = 4096;
static constexpr int BM = 128;
static constexpr int BN = 128;
static constexpr int BK = 64;

typedef __attribute__((ext_vector_type(8))) short short8;
typedef __attribute__((ext_vector_type(4))) float float4v;
typedef __attribute__((ext_vector_type(4))) int int4v;
typedef __attribute__((ext_vector_type(8))) unsigned short ushort8;

__device__ __forceinline__ unsigned short f32_to_bf16(float f) {
  union { float f; uint32_t u; } c; c.f = f;
  uint32_t u = c.u;
  u += 0x7fffu + ((u >> 16) & 1u);   // round-to-nearest-even (no NaNs in data)
  return (unsigned short)(u >> 16);
}

// ---------------------------------------------------------------------------
// Mask element-width detection. numpy bool_ = 1 byte; int32/float32 promotion
// would zero byte positions ==1 (mod 4). 10% density over 1M positions ->
// ~105k hits for byte layout, exactly 0 for 4-byte layouts.
// ---------------------------------------------------------------------------
__global__ void detect_mask_kernel(const unsigned char* __restrict__ m, int* __restrict__ flag) {
  int found = 0;
  const int total = 1 << 20;  // scan first 4 MiB
  for (int p = blockIdx.x * blockDim.x + threadIdx.x; p < total;
       p += gridDim.x * blockDim.x)
    found |= (m[4 * p + 1] != 0);
  if (__any(found) && (threadIdx.x & 63) == 0) atomicOr(flag, 1);
}

// x fp32 -> bf16, 8 elements/thread (two 16B loads, one 16B store)
__global__ void cvt_x_kernel(const float* __restrict__ x, unsigned short* __restrict__ o) {
  long i = (blockIdx.x * (long)blockDim.x + threadIdx.x) * 8;
  float4v v0 = *(const float4v*)(x + i);
  float4v v1 = *(const float4v*)(x + i + 4);
  ushort8 r;
  r[0] = f32_to_bf16(v0[0]); r[1] = f32_to_bf16(v0[1]);
  r[2] = f32_to_bf16(v0[2]); r[3] = f32_to_bf16(v0[3]);
  r[4] = f32_to_bf16(v1[0]); r[5] = f32_to_bf16(v1[1]);
  r[6] = f32_to_bf16(v1[2]); r[7] = f32_to_bf16(v1[3]);
  *(ushort8*)(o + i) = r;
}

// W fp32 * mask -> bf16, 8 elements/thread; mask layout chosen by *flag
__global__ void cvt_w_kernel(const float* __restrict__ w, const unsigned char* __restrict__ mraw,
                             const int* __restrict__ flag, unsigned short* __restrict__ o) {
  long i = (blockIdx.x * (long)blockDim.x + threadIdx.x) * 8;
  float4v w0 = *(const float4v*)(w + i);
  float4v w1 = *(const float4v*)(w + i + 4);
  int m[8];
  if (*flag) {  // 1-byte elements
    unsigned long long mb = *(const unsigned long long*)(mraw + i);
#pragma unroll
    for (int j = 0; j < 8; ++j) m[j] = ((mb >> (8 * j)) & 0xffull) != 0;
  } else {      // 4-byte elements (int32 0/1 or float32 0.0/1.0 — both: nonzero word)
    int4v a = *(const int4v*)((const int*)mraw + i);
    int4v b = *(const int4v*)((const int*)mraw + i + 4);
#pragma unroll
    for (int j = 0; j < 4; ++j) { m[j] = a[j] != 0; m[4 + j] = b[j] != 0; }
  }
  ushort8 r;
  r[0] = f32_to_bf16(m[0] ? w0[0] : 0.0f);
  r[1] = f32_to_bf16(m[1] ? w0[1] : 0.0f);
  r[2] = f32_to_bf16(m[2] ? w0[2] : 0.0f);
  r[3] = f32_to_bf16(m[3] ? w0[3] : 0.0f);
  r[4] = f32_to_bf16(m[4] ? w1[0] : 0.0f);
  r[5] = f32_to_bf16(m[5] ? w1[1] : 0.0f);
  r[6] = f32_to_bf16(m[6] ? w1[2] : 0.0f);
  r[7] = f32_to_bf16(m[7] ? w1[3] : 0.0f);
  *(ushort8*)(o + i) = r;
}

// ---------------------------------------------------------------------------
// bf16 MFMA GEMM, B^T form: O[m][n] = sum_k X[m][k]*W[n][k].
// 256 threads = 4 waves; each wave computes 64x64 via 4x4 grid of 16x16x32.
// LDS tiles row-major [row][64], with 16B chunks XOR-swizzled within a row:
// LDS position j of row r holds global chunk j ^ (r & 7). Staged with
// global_load_lds width 16 (lane-contiguous LDS destination mandatory).
// ---------------------------------------------------------------------------
__global__ __launch_bounds__(256) void gemm_bt_kernel(const unsigned short* __restrict__ X,
                                                      const unsigned short* __restrict__ W,
                                                      float* __restrict__ O) {
  __shared__ short sA[BM * BK];  // 16 KiB
  __shared__ short sB[BN * BK];  // 16 KiB

  const int tid = threadIdx.x;
  const int lane = tid & 63;
  const int wave = tid >> 6;
  const int wr = wave >> 1;   // 0..1: which 64-row half
  const int wc = wave & 1;    // 0..1: which 64-col half

  const int tnCount = Ndim / BN;  // 32
  const int tm = blockIdx.x / tnCount;
  const int tn = blockIdx.x % tnCount;
  const int row0 = tm * BM;
  const int col0 = tn * BN;

  float4v acc[4][4];
#pragma unroll
  for (int i = 0; i < 4; ++i)
#pragma unroll
    for (int j = 0; j < 4; ++j) acc[i][j] = (float4v){0.f, 0.f, 0.f, 0.f};

  int srow[4], scol[4];
#pragma unroll
  for (int r = 0; r < 4; ++r) {
    int c = r * 256 + tid;                       // 16B-chunk id within tile
    srow[r] = c >> 3;                            // 8 chunks per 64-elem row
    scol[r] = (((c & 7) ^ (srow[r] & 7)) * 8);   // XOR-swizzled global chunk
  }

  const int rsel = lane & 15;         // fragment row (m or n) within 16
  const int q0 = lane >> 4;           // fragment k-chunk within 4-chunk group
  const int sw = rsel & 7;            // swizzle key (row&7; wr*64+i*16 ≡ 0 mod 8)

  for (int kt = 0; kt < Kdim; kt += BK) {
#pragma unroll
    for (int r = 0; r < 4; ++r) {
      const unsigned short* gA = X + (long)(row0 + srow[r]) * Kdim + kt + scol[r];
      const unsigned short* gB = W + (long)(col0 + srow[r]) * Kdim + kt + scol[r];
      const int loff = (r * 256 + tid) * 16;
      __builtin_amdgcn_global_load_lds((const __attribute__((address_space(1))) void*)gA,
                                       (__attribute__((address_space(3))) void*)((char*)sA + loff),
                                       16, 0, 0);
      __builtin_amdgcn_global_load_lds((const __attribute__((address_space(1))) void*)gB,
                                       (__attribute__((address_space(3))) void*)((char*)sB + loff),
                                       16, 0, 0);
    }
    __syncthreads();

#pragma unroll
    for (int ks = 0; ks < 2; ++ks) {            // two 32-wide K steps
      const int pos = ((ks * 4 + q0) ^ sw) * 8; // swizzled chunk offset (elems)
      short8 a[4], b[4];
#pragma unroll
      for (int i = 0; i < 4; ++i)
        a[i] = *(const short8*)(sA + (wr * 64 + i * 16 + rsel) * BK + pos);
#pragma unroll
      for (int j = 0; j < 4; ++j)
        b[j] = *(const short8*)(sB + (wc * 64 + j * 16 + rsel) * BK + pos);
#pragma unroll
      for (int i = 0; i < 4; ++i)
#pragma unroll
        for (int j = 0; j < 4; ++j)
          acc[i][j] = __builtin_amdgcn_mfma_f32_16x16x32_bf16(a[i], b[j], acc[i][j], 0, 0, 0);
    }
    __syncthreads();
  }

  // C/D layout (verified m89/m91): col = lane&15, row = (lane>>4)*4 + reg
  const int ccol = lane & 15;
  const int crow = (lane >> 4) * 4;
#pragma unroll
  for (int i = 0; i < 4; ++i) {
#pragma unroll
    for (int j = 0; j < 4; ++j) {
      const long rbase = row0 + wr * 64 + i * 16 + crow;
      const long cg = col0 + wc * 64 + j * 16 + ccol;
#pragma unroll
      for (int r = 0; r < 4; ++r)
        O[(rbase + r) * (long)Ndim + cg] = acc[i][j][r];
    }
  }
}

// ---------------------------------------------------------------------------
// Fallback (only if ws too small for bf16 staging): fp32 LDS-tiled GEMM.
// ---------------------------------------------------------------------------
__global__ void gemm_fallback_kernel(const float* __restrict__ X, const float* __restrict__ Wt,
                                     const unsigned char* __restrict__ mraw,
                                     const int* __restrict__ flag, float* __restrict__ O) {
  __shared__ float sX[16][17];
  __shared__ float sW[16][17];
  const int tx = threadIdx.x & 15;
  const int ty = threadIdx.x >> 4;
  const long row = blockIdx.y * 16 + ty;
  const long colblock = blockIdx.x * 16;
  const int byteLayout = *flag;
  float acc = 0.f;
  for (int k0 = 0; k0 < Kdim; k0 += 16) {
    sX[ty][tx] = X[row * Kdim + k0 + tx];
    const long wi = (colblock + ty) * (long)Kdim + k0 + tx;
    const int mv = byteLayout ? (mraw[wi] != 0) : (((const int*)mraw)[wi] != 0);
    sW[ty][tx] = mv ? Wt[wi] : 0.f;
    __syncthreads();
#pragma unroll
    for (int k = 0; k < 16; ++k) acc += sX[ty][k] * sW[tx][k];
    __syncthreads();
  }
  O[row * Ndim + colblock + tx] = acc;
}

extern "C" void kernel_launch(void* const* d_in, const int* in_sizes, int n_in,
                              void* d_out, int out_size, void* d_ws, size_t ws_size,
                              hipStream_t stream) {
  const float* x = (const float*)d_in[0];               // [8192, 4096] fp32
  const float* w = (const float*)d_in[1];               // [4096, 4096] fp32
  const unsigned char* mask = (const unsigned char*)d_in[2];  // bool (layout detected)
  float* out = (float*)d_out;                           // [8192, 4096] fp32

  const size_t xb_off = 0;
  const size_t wb_off = (size_t)Mdim * Kdim * 2;             // 67,108,864
  const size_t flag_off = wb_off + (size_t)Ndim * Kdim * 2;  // 100,663,296
  const size_t needed = flag_off + 16;

  if (ws_size >= needed) {
    unsigned short* xb = (unsigned short*)((char*)d_ws + xb_off);
    unsigned short* wb = (unsigned short*)((char*)d_ws + wb_off);
    int* flag = (int*)((char*)d_ws + flag_off);

    hipMemsetAsync(flag, 0, sizeof(int), stream);
    detect_mask_kernel<<<64, 256, 0, stream>>>(mask, flag);
    cvt_x_kernel<<<(int)(((long)Mdim * Kdim / 8) / 256), 256, 0, stream>>>(x, xb);
    cvt_w_kernel<<<(int)(((long)Ndim * Kdim / 8) / 256), 256, 0, stream>>>(w, mask, flag, wb);
    gemm_bt_kernel<<<(Mdim / BM) * (Ndim / BN), 256, 0, stream>>>(xb, wb, out);
  } else {
    int* flag = (int*)d_ws;
    hipMemsetAsync(flag, 0, sizeof(int), stream);
    detect_mask_kernel<<<64, 256, 0, stream>>>(mask, flag);
    dim3 grid(Ndim / 16, Mdim / 16);
    gemm_fallback_kernel<<<grid, 256, 0, stream>>>(x, w, mask, flag, out);
  }
}

// Round 3
// 612.227 us; speedup vs baseline: 1.1906x; 1.1543x over previous
//
#include <hip/hip_runtime.h>
#include <stdint.h>

// SparseLinear: out[m][n] = sum_k x[m][k] * W[n][k] * mask[n][k]
// M = B*S = 8192, N = 4096, K = 4096, fp32 in/out, bf16-tolerance check.
// R2: (a) MFMA shape 16x16x32 -> 32x32x16 (fewer issue cycles per K-iter,
// higher-ceiling pipe; C/D layout HW-verified m74/m101); (b) L2-locality
// block swizzle (512-block groups cover 16x32 tile region).
// R1's XOR-swizzled LDS chunk placement kept (conflicts 1e8 -> 0).

static constexpr int Mdim = 8192;
static constexpr int Ndim = 4096;
static constexpr int Kdim = 4096;
static constexpr int BM = 128;
static constexpr int BN = 128;
static constexpr int BK = 64;

typedef __attribute__((ext_vector_type(8))) short short8;
typedef __attribute__((ext_vector_type(4))) float float4v;
typedef __attribute__((ext_vector_type(16))) float float16v;
typedef __attribute__((ext_vector_type(4))) int int4v;
typedef __attribute__((ext_vector_type(8))) unsigned short ushort8;

__device__ __forceinline__ unsigned short f32_to_bf16(float f) {
  union { float f; uint32_t u; } c; c.f = f;
  uint32_t u = c.u;
  u += 0x7fffu + ((u >> 16) & 1u);   // round-to-nearest-even (no NaNs in data)
  return (unsigned short)(u >> 16);
}

// ---------------------------------------------------------------------------
// Mask element-width detection. numpy bool_ = 1 byte; int32/float32 promotion
// would zero byte positions ==1 (mod 4). 10% density over 1M positions ->
// ~105k hits for byte layout, exactly 0 for 4-byte layouts.
// ---------------------------------------------------------------------------
__global__ void detect_mask_kernel(const unsigned char* __restrict__ m, int* __restrict__ flag) {
  int found = 0;
  const int total = 1 << 20;  // scan first 4 MiB
  for (int p = blockIdx.x * blockDim.x + threadIdx.x; p < total;
       p += gridDim.x * blockDim.x)
    found |= (m[4 * p + 1] != 0);
  if (__any(found) && (threadIdx.x & 63) == 0) atomicOr(flag, 1);
}

// x fp32 -> bf16, 8 elements/thread (two 16B loads, one 16B store)
__global__ void cvt_x_kernel(const float* __restrict__ x, unsigned short* __restrict__ o) {
  long i = (blockIdx.x * (long)blockDim.x + threadIdx.x) * 8;
  float4v v0 = *(const float4v*)(x + i);
  float4v v1 = *(const float4v*)(x + i + 4);
  ushort8 r;
  r[0] = f32_to_bf16(v0[0]); r[1] = f32_to_bf16(v0[1]);
  r[2] = f32_to_bf16(v0[2]); r[3] = f32_to_bf16(v0[3]);
  r[4] = f32_to_bf16(v1[0]); r[5] = f32_to_bf16(v1[1]);
  r[6] = f32_to_bf16(v1[2]); r[7] = f32_to_bf16(v1[3]);
  *(ushort8*)(o + i) = r;
}

// W fp32 * mask -> bf16, 8 elements/thread; mask layout chosen by *flag
__global__ void cvt_w_kernel(const float* __restrict__ w, const unsigned char* __restrict__ mraw,
                             const int* __restrict__ flag, unsigned short* __restrict__ o) {
  long i = (blockIdx.x * (long)blockDim.x + threadIdx.x) * 8;
  float4v w0 = *(const float4v*)(w + i);
  float4v w1 = *(const float4v*)(w + i + 4);
  int m[8];
  if (*flag) {  // 1-byte elements
    unsigned long long mb = *(const unsigned long long*)(mraw + i);
#pragma unroll
    for (int j = 0; j < 8; ++j) m[j] = ((mb >> (8 * j)) & 0xffull) != 0;
  } else {      // 4-byte elements (int32 0/1 or float32 0.0/1.0 — both: nonzero word)
    int4v a = *(const int4v*)((const int*)mraw + i);
    int4v b = *(const int4v*)((const int*)mraw + i + 4);
#pragma unroll
    for (int j = 0; j < 4; ++j) { m[j] = a[j] != 0; m[4 + j] = b[j] != 0; }
  }
  ushort8 r;
  r[0] = f32_to_bf16(m[0] ? w0[0] : 0.0f);
  r[1] = f32_to_bf16(m[1] ? w0[1] : 0.0f);
  r[2] = f32_to_bf16(m[2] ? w0[2] : 0.0f);
  r[3] = f32_to_bf16(m[3] ? w0[3] : 0.0f);
  r[4] = f32_to_bf16(m[4] ? w1[0] : 0.0f);
  r[5] = f32_to_bf16(m[5] ? w1[1] : 0.0f);
  r[6] = f32_to_bf16(m[6] ? w1[2] : 0.0f);
  r[7] = f32_to_bf16(m[7] ? w1[3] : 0.0f);
  *(ushort8*)(o + i) = r;
}

// ---------------------------------------------------------------------------
// bf16 MFMA GEMM, B^T form: O[m][n] = sum_k X[m][k]*W[n][k].
// 256 threads = 4 waves in 2x2; each wave computes 64x64 as 2x2 of 32x32x16.
// A/B fragment layout (gfx950 2xK pattern, m89-analog): m/n = lane&31,
// k = (lane>>5)*8 + i (8 contiguous bf16 -> one ds_read_b128).
// C/D layout (m74/m101): col = lane&31, row = (reg&3) + 8*(reg>>2) + 4*(lane>>5).
// LDS tiles row-major [row][64], 16B chunks XOR-swizzled: LDS chunk j of row r
// holds global chunk j ^ (r & 7) (global_load_lds dest must be lane-contiguous).
// ---------------------------------------------------------------------------
__global__ __launch_bounds__(256) void gemm_bt_kernel(const unsigned short* __restrict__ X,
                                                      const unsigned short* __restrict__ W,
                                                      float* __restrict__ O) {
  __shared__ short sA[BM * BK];  // 16 KiB
  __shared__ short sB[BN * BK];  // 16 KiB

  const int tid = threadIdx.x;
  const int lane = tid & 63;
  const int wave = tid >> 6;
  const int wr = wave >> 1;   // 0..1: which 64-row half
  const int wc = wave & 1;    // 0..1: which 64-col half

  // L2-locality swizzle: 512-block groups each cover 16 tm x 32 tn, so a
  // resident dispatch wave touches a compact xb band + wb band (~32 MB).
  const int bid = blockIdx.x;
  const int grp512 = bid >> 9;
  const int rres = bid & 511;
  const int tm = (grp512 << 4) | (rres & 15);
  const int tn = rres >> 4;
  const int row0 = tm * BM;
  const int col0 = tn * BN;

  float16v acc[2][2];
#pragma unroll
  for (int i = 0; i < 2; ++i)
#pragma unroll
    for (int j = 0; j < 2; ++j)
#pragma unroll
      for (int r = 0; r < 16; ++r) acc[i][j][r] = 0.f;

  int srow[4], scol[4];
#pragma unroll
  for (int r = 0; r < 4; ++r) {
    int c = r * 256 + tid;                       // 16B-chunk id within tile
    srow[r] = c >> 3;                            // 8 chunks per 64-elem row
    scol[r] = (((c & 7) ^ (srow[r] & 7)) * 8);   // XOR-swizzled global chunk
  }

  const int ml = lane & 31;       // fragment row (m or n) within 32
  const int kg = lane >> 5;       // k-group: chunk parity within 16-wide K step
  const int sw = lane & 7;        // swizzle key (row&7; wr*64+i*32 ≡ 0 mod 8)

  for (int kt = 0; kt < Kdim; kt += BK) {
#pragma unroll
    for (int r = 0; r < 4; ++r) {
      const unsigned short* gA = X + (long)(row0 + srow[r]) * Kdim + kt + scol[r];
      const unsigned short* gB = W + (long)(col0 + srow[r]) * Kdim + kt + scol[r];
      const int loff = (r * 256 + tid) * 16;
      __builtin_amdgcn_global_load_lds((const __attribute__((address_space(1))) void*)gA,
                                       (__attribute__((address_space(3))) void*)((char*)sA + loff),
                                       16, 0, 0);
      __builtin_amdgcn_global_load_lds((const __attribute__((address_space(1))) void*)gB,
                                       (__attribute__((address_space(3))) void*)((char*)sB + loff),
                                       16, 0, 0);
    }
    __syncthreads();

#pragma unroll
    for (int s = 0; s < 4; ++s) {                     // four 16-wide K steps
      const int pos = ((((s << 1) | kg) ^ sw) << 3);  // swizzled chunk offset (elems)
      short8 a[2], b[2];
#pragma unroll
      for (int i = 0; i < 2; ++i)
        a[i] = *(const short8*)(sA + (wr * 64 + i * 32 + ml) * BK + pos);
#pragma unroll
      for (int j = 0; j < 2; ++j)
        b[j] = *(const short8*)(sB + (wc * 64 + j * 32 + ml) * BK + pos);
#pragma unroll
      for (int i = 0; i < 2; ++i)
#pragma unroll
        for (int j = 0; j < 2; ++j)
          acc[i][j] = __builtin_amdgcn_mfma_f32_32x32x16_bf16(a[i], b[j], acc[i][j], 0, 0, 0);
    }
    __syncthreads();
  }

  // C/D layout (verified m74/m101): col = lane&31,
  // row = (reg&3) + 8*(reg>>2) + 4*(lane>>5)
#pragma unroll
  for (int i = 0; i < 2; ++i) {
#pragma unroll
    for (int j = 0; j < 2; ++j) {
      const long rbase = row0 + wr * 64 + i * 32;
      const long cg = col0 + wc * 64 + j * 32 + ml;
#pragma unroll
      for (int reg = 0; reg < 16; ++reg) {
        const long row = rbase + (reg & 3) + 8 * (reg >> 2) + 4 * kg;
        O[row * (long)Ndim + cg] = acc[i][j][reg];
      }
    }
  }
}

// ---------------------------------------------------------------------------
// Fallback (only if ws too small for bf16 staging): fp32 LDS-tiled GEMM.
// ---------------------------------------------------------------------------
__global__ void gemm_fallback_kernel(const float* __restrict__ X, const float* __restrict__ Wt,
                                     const unsigned char* __restrict__ mraw,
                                     const int* __restrict__ flag, float* __restrict__ O) {
  __shared__ float sX[16][17];
  __shared__ float sW[16][17];
  const int tx = threadIdx.x & 15;
  const int ty = threadIdx.x >> 4;
  const long row = blockIdx.y * 16 + ty;
  const long colblock = blockIdx.x * 16;
  const int byteLayout = *flag;
  float acc = 0.f;
  for (int k0 = 0; k0 < Kdim; k0 += 16) {
    sX[ty][tx] = X[row * Kdim + k0 + tx];
    const long wi = (colblock + ty) * (long)Kdim + k0 + tx;
    const int mv = byteLayout ? (mraw[wi] != 0) : (((const int*)mraw)[wi] != 0);
    sW[ty][tx] = mv ? Wt[wi] : 0.f;
    __syncthreads();
#pragma unroll
    for (int k = 0; k < 16; ++k) acc += sX[ty][k] * sW[tx][k];
    __syncthreads();
  }
  O[row * Ndim + colblock + tx] = acc;
}

extern "C" void kernel_launch(void* const* d_in, const int* in_sizes, int n_in,
                              void* d_out, int out_size, void* d_ws, size_t ws_size,
                              hipStream_t stream) {
  const float* x = (const float*)d_in[0];               // [8192, 4096] fp32
  const float* w = (const float*)d_in[1];               // [4096, 4096] fp32
  const unsigned char* mask = (const unsigned char*)d_in[2];  // bool (layout detected)
  float* out = (float*)d_out;                           // [8192, 4096] fp32

  const size_t xb_off = 0;
  const size_t wb_off = (size_t)Mdim * Kdim * 2;             // 67,108,864
  const size_t flag_off = wb_off + (size_t)Ndim * Kdim * 2;  // 100,663,296
  const size_t needed = flag_off + 16;

  if (ws_size >= needed) {
    unsigned short* xb = (unsigned short*)((char*)d_ws + xb_off);
    unsigned short* wb = (unsigned short*)((char*)d_ws + wb_off);
    int* flag = (int*)((char*)d_ws + flag_off);

    hipMemsetAsync(flag, 0, sizeof(int), stream);
    detect_mask_kernel<<<64, 256, 0, stream>>>(mask, flag);
    cvt_x_kernel<<<(int)(((long)Mdim * Kdim / 8) / 256), 256, 0, stream>>>(x, xb);
    cvt_w_kernel<<<(int)(((long)Ndim * Kdim / 8) / 256), 256, 0, stream>>>(w, mask, flag, wb);
    gemm_bt_kernel<<<(Mdim / BM) * (Ndim / BN), 256, 0, stream>>>(xb, wb, out);
  } else {
    int* flag = (int*)d_ws;
    hipMemsetAsync(flag, 0, sizeof(int), stream);
    detect_mask_kernel<<<64, 256, 0, stream>>>(mask, flag);
    dim3 grid(Ndim / 16, Mdim / 16);
    gemm_fallback_kernel<<<grid, 256, 0, stream>>>(x, w, mask, flag, out);
  }
}